// Round 1
// baseline (1953.245 us; speedup 1.0000x reference)
//
#include <hip/hip_runtime.h>
#include <cmath>

#define NN 50000
#define EE 800000
#define ET 850000   // EE + NN self-loops

// ---------------- CSR build ----------------
__global__ void k_zero(int* __restrict__ p, int n){
  int i = blockIdx.x*256 + threadIdx.x;
  if (i < n) p[i] = 0;
}

__global__ void k_hist(const int* __restrict__ ei, int* __restrict__ count){
  int e = blockIdx.x*256 + threadIdx.x;
  if (e >= ET) return;
  int d = (e < EE) ? ei[EE + e] : (e - EE);
  atomicAdd(&count[d], 1);
}

__global__ void k_bsum(const int* __restrict__ count, int* __restrict__ bsums){
  int i = blockIdx.x*256 + threadIdx.x;
  int v = (i < NN) ? count[i] : 0;
  #pragma unroll
  for (int m = 1; m < 64; m <<= 1) v += __shfl_xor(v, m);
  __shared__ int ws[4];
  if ((threadIdx.x & 63) == 0) ws[threadIdx.x >> 6] = v;
  __syncthreads();
  if (threadIdx.x == 0) bsums[blockIdx.x] = ws[0] + ws[1] + ws[2] + ws[3];
}

__global__ void k_bscan(const int* __restrict__ bsums, int* __restrict__ boffs, int nb){
  __shared__ int tmp[256];
  int t = threadIdx.x;
  int self = (t < nb) ? bsums[t] : 0;
  int v = self;
  for (int off = 1; off < 256; off <<= 1){
    tmp[t] = v; __syncthreads();
    int add = (t >= off) ? tmp[t - off] : 0;
    __syncthreads();
    v += add;
  }
  if (t < nb) boffs[t] = v - self;   // exclusive
}

__global__ void k_scan(const int* __restrict__ count, const int* __restrict__ boffs,
                       int* __restrict__ offs, int* __restrict__ cursor){
  __shared__ int tmp[256];
  int t = threadIdx.x;
  int gid = blockIdx.x*256 + t;
  int self = (gid < NN) ? count[gid] : 0;
  int v = self;
  for (int off = 1; off < 256; off <<= 1){
    tmp[t] = v; __syncthreads();
    int add = (t >= off) ? tmp[t - off] : 0;
    __syncthreads();
    v += add;
  }
  int excl = v - self + boffs[blockIdx.x];
  if (gid < NN){ offs[gid] = excl; cursor[gid] = excl; }
  if (gid == 0) offs[NN] = ET;
}

__global__ void k_scatter(const int* __restrict__ ei, int* __restrict__ cursor,
                          int* __restrict__ srcCSR){
  int e = blockIdx.x*256 + threadIdx.x;
  if (e >= ET) return;
  int s, d;
  if (e < EE){ s = ei[e]; d = ei[EE + e]; } else { s = d = e - EE; }
  int pos = atomicAdd(&cursor[d], 1);
  srcCSR[pos] = s;
}

// ---------------- compute ----------------
__device__ __forceinline__ float redsum32(float p){
  p += __shfl_xor(p, 1);
  p += __shfl_xor(p, 2);
  p += __shfl_xor(p, 4);
  p += __shfl_xor(p, 8);
  p += __shfl_xor(p, 16);
  return p;   // all 32 lanes of the half-wave hold the sum (masks<=16 never cross bit 5)
}

// h0 = x@W0 + b0 ; hp0 = h0@Ws[0] ; hl0 = hp0.att_l[0] ; hr0 = hp0.att_r[0]
__global__ __launch_bounds__(256) void k_prologue(
    const float* __restrict__ x, const float* __restrict__ W0, const float* __restrict__ b0,
    const float* __restrict__ Ws0, const float* __restrict__ al0, const float* __restrict__ ar0,
    float* __restrict__ hp_out, float* __restrict__ hl_out, float* __restrict__ hr_out){
  __shared__ float w0[128*32];
  __shared__ float w1[32*32];
  int t = threadIdx.x;
  for (int i = t; i < 4096; i += 256) w0[i] = W0[i];
  for (int i = t; i < 1024; i += 256) w1[i] = Ws0[i];
  __syncthreads();
  int g = t >> 5, lane = t & 31;
  int n = blockIdx.x*8 + g;                 // 6250*8 == 50000, no bounds check
  const float4* x4 = (const float4*)(x + (size_t)n*128);
  float h = b0[lane];
  #pragma unroll
  for (int j4 = 0; j4 < 32; ++j4){
    float4 xv = x4[j4];
    h += xv.x * w0[(j4*4+0)*32 + lane];
    h += xv.y * w0[(j4*4+1)*32 + lane];
    h += xv.z * w0[(j4*4+2)*32 + lane];
    h += xv.w * w0[(j4*4+3)*32 + lane];
  }
  float hp = 0.f;
  #pragma unroll
  for (int j = 0; j < 32; ++j) hp += __shfl(h, j, 32) * w1[j*32 + lane];
  float tl = hp*al0[lane], tr = hp*ar0[lane];
  #pragma unroll
  for (int m = 1; m < 32; m <<= 1){ tl += __shfl_xor(tl, m); tr += __shfl_xor(tr, m); }
  hp_out[(size_t)n*32 + lane] = hp;
  if (lane == 0){ hl_out[n] = tl; hr_out[n] = tr; }
}

// One SuperGAT layer, fused: segment softmax (online, 2-pass w/ recompute) +
// aggregation + relu(agg + b) + NEXT layer's hp/hl/hr (or final 32x16 linear).
__global__ __launch_bounds__(256) void k_layer(
    const float* __restrict__ hp, const float* __restrict__ hl, const float* __restrict__ hr,
    const int* __restrict__ offs, const int* __restrict__ srcCSR,
    const float* __restrict__ bcur,
    const float* __restrict__ Wn, const float* __restrict__ aln, const float* __restrict__ arn,
    const float* __restrict__ b16,
    float* __restrict__ hp_out, float* __restrict__ hl_out, float* __restrict__ hr_out,
    float* __restrict__ final_out, int last){
  __shared__ float wl[1024];
  int t = threadIdx.x;
  int nW = last ? 512 : 1024;
  for (int i = t; i < nW; i += 256) wl[i] = Wn[i];
  __syncthreads();
  int g = t >> 5, lane = t & 31;
  int d = blockIdx.x*8 + g;
  float hpd = hp[(size_t)d*32 + lane];
  float hrd = hr[d];
  int beg = offs[d], end = offs[d+1];

  // pass 1: online softmax stats (all 32 lanes keep identical m/ssum)
  float m = -INFINITY, ssum = 0.f;
  for (int i = beg; i < end; ++i){
    int s = srcCSR[i];
    float v = hp[(size_t)s*32 + lane];
    float p = redsum32(v * hpd);
    float a = (hl[s] + hrd) * (1.f/(1.f + __expf(-p)));
    a = (a >= 0.f) ? a : 0.2f*a;
    float mn = fmaxf(m, a);
    ssum = ssum*__expf(m - mn) + __expf(a - mn);
    m = mn;
  }
  float rs = 1.f/ssum;

  // pass 2: recompute alpha (loads shared with aggregation anyway), accumulate
  float acc = 0.f;
  for (int i = beg; i < end; ++i){
    int s = srcCSR[i];
    float v = hp[(size_t)s*32 + lane];
    float p = redsum32(v * hpd);
    float a = (hl[s] + hrd) * (1.f/(1.f + __expf(-p)));
    a = (a >= 0.f) ? a : 0.2f*a;
    acc += v * (__expf(a - m) * rs);
  }
  float hnew = fmaxf(acc + bcur[lane], 0.f);

  if (!last){
    float hpn = 0.f;
    #pragma unroll
    for (int j = 0; j < 32; ++j) hpn += __shfl(hnew, j, 32) * wl[j*32 + lane];
    float tl = hpn*aln[lane], tr = hpn*arn[lane];
    #pragma unroll
    for (int mm = 1; mm < 32; mm <<= 1){ tl += __shfl_xor(tl, mm); tr += __shfl_xor(tr, mm); }
    hp_out[(size_t)d*32 + lane] = hpn;
    if (lane == 0){ hl_out[d] = tl; hr_out[d] = tr; }
  } else {
    int k = lane & 15;
    float o = b16[k];
    #pragma unroll
    for (int j = 0; j < 32; ++j) o += __shfl(hnew, j, 32) * wl[j*16 + k];
    if (lane < 16) final_out[(size_t)d*16 + lane] = o;
  }
}

extern "C" void kernel_launch(void* const* d_in, const int* in_sizes, int n_in,
                              void* d_out, int out_size, void* d_ws, size_t ws_size,
                              hipStream_t stream){
  const float* x   = (const float*)d_in[0];
  const int*   ei  = (const int*)  d_in[1];
  const float* W0  = (const float*)d_in[2];
  const float* b0  = (const float*)d_in[3];
  const float* Ws  = (const float*)d_in[4];
  const float* al  = (const float*)d_in[5];
  const float* ar  = (const float*)d_in[6];
  const float* bs  = (const float*)d_in[7];
  const float* W16 = (const float*)d_in[8];
  const float* b16 = (const float*)d_in[9];
  float* out = (float*)d_out;

  char* w = (char*)d_ws;
  int* count   = (int*)w;   w += 50176*sizeof(int);
  int* offs    = (int*)w;   w += 50176*sizeof(int);
  int* cursor  = (int*)w;   w += 50176*sizeof(int);
  int* srcCSR  = (int*)w;   w += 850048*sizeof(int);
  int* bsums   = (int*)w;   w += 256*sizeof(int);
  int* boffs   = (int*)w;   w += 256*sizeof(int);
  float* hpA   = (float*)w; w += (size_t)NN*32*sizeof(float);
  float* hpB   = (float*)w; w += (size_t)NN*32*sizeof(float);
  float* hlA   = (float*)w; w += 50176*sizeof(float);
  float* hrA   = (float*)w; w += 50176*sizeof(float);
  float* hlB   = (float*)w; w += 50176*sizeof(float);
  float* hrB   = (float*)w; w += 50176*sizeof(float);
  // total ~17.6 MB of d_ws

  // CSR build (rebuilt every call; ws is re-poisoned by the harness)
  k_zero   <<<196, 256, 0, stream>>>(count, NN);
  k_hist   <<<3321,256, 0, stream>>>(ei, count);
  k_bsum   <<<196, 256, 0, stream>>>(count, bsums);
  k_bscan  <<<1,   256, 0, stream>>>(bsums, boffs, 196);
  k_scan   <<<196, 256, 0, stream>>>(count, boffs, offs, cursor);
  k_scatter<<<3321,256, 0, stream>>>(ei, cursor, srcCSR);

  // h0 = x@W0+b0 fused with layer-0 transform
  k_prologue<<<6250, 256, 0, stream>>>(x, W0, b0, Ws, al, ar, hpA, hlA, hrA);

  for (int l = 0; l < 15; ++l){
    const float* hin  = (l & 1) ? hpB : hpA;
    const float* hlin = (l & 1) ? hlB : hlA;
    const float* hrin = (l & 1) ? hrB : hrA;
    float* hout  = (l & 1) ? hpA : hpB;
    float* hlout = (l & 1) ? hlA : hlB;
    float* hrout = (l & 1) ? hrA : hrB;
    int last = (l == 14);
    const float* Wn  = last ? W16 : (Ws + (size_t)(l+1)*1024);
    const float* aln = last ? al  : (al + (size_t)(l+1)*32);
    const float* arn = last ? ar  : (ar + (size_t)(l+1)*32);
    k_layer<<<6250, 256, 0, stream>>>(hin, hlin, hrin, offs, srcCSR,
                                      bs + (size_t)l*32,
                                      Wn, aln, arn, b16,
                                      hout, hlout, hrout, out, last);
  }
}

// Round 2
// 1276.569 us; speedup vs baseline: 1.5301x; 1.5301x over previous
//
#include <hip/hip_runtime.h>
#include <cmath>

#define NN 50000
#define EE 800000
#define ET 850000   // EE + NN self-loops

// ---------------- CSR build ----------------
__global__ void k_zero(int* __restrict__ p, int n){
  int i = blockIdx.x*256 + threadIdx.x;
  if (i < n) p[i] = 0;
}

__global__ void k_hist(const int* __restrict__ ei, int* __restrict__ count){
  int e = blockIdx.x*256 + threadIdx.x;
  if (e >= ET) return;
  int d = (e < EE) ? ei[EE + e] : (e - EE);
  atomicAdd(&count[d], 1);
}

__global__ void k_bsum(const int* __restrict__ count, int* __restrict__ bsums){
  int i = blockIdx.x*256 + threadIdx.x;
  int v = (i < NN) ? count[i] : 0;
  #pragma unroll
  for (int m = 1; m < 64; m <<= 1) v += __shfl_xor(v, m);
  __shared__ int ws[4];
  if ((threadIdx.x & 63) == 0) ws[threadIdx.x >> 6] = v;
  __syncthreads();
  if (threadIdx.x == 0) bsums[blockIdx.x] = ws[0] + ws[1] + ws[2] + ws[3];
}

__global__ void k_bscan(const int* __restrict__ bsums, int* __restrict__ boffs, int nb){
  __shared__ int tmp[256];
  int t = threadIdx.x;
  int self = (t < nb) ? bsums[t] : 0;
  int v = self;
  for (int off = 1; off < 256; off <<= 1){
    tmp[t] = v; __syncthreads();
    int add = (t >= off) ? tmp[t - off] : 0;
    __syncthreads();
    v += add;
  }
  if (t < nb) boffs[t] = v - self;   // exclusive
}

__global__ void k_scan(const int* __restrict__ count, const int* __restrict__ boffs,
                       int* __restrict__ offs, int* __restrict__ cursor){
  __shared__ int tmp[256];
  int t = threadIdx.x;
  int gid = blockIdx.x*256 + t;
  int self = (gid < NN) ? count[gid] : 0;
  int v = self;
  for (int off = 1; off < 256; off <<= 1){
    tmp[t] = v; __syncthreads();
    int add = (t >= off) ? tmp[t - off] : 0;
    __syncthreads();
    v += add;
  }
  int excl = v - self + boffs[blockIdx.x];
  if (gid < NN){ offs[gid] = excl; cursor[gid] = excl; }
  if (gid == 0) offs[NN] = ET;
}

__global__ void k_scatter(const int* __restrict__ ei, int* __restrict__ cursor,
                          int* __restrict__ srcCSR){
  int e = blockIdx.x*256 + threadIdx.x;
  if (e >= ET) return;
  int s, d;
  if (e < EE){ s = ei[e]; d = ei[EE + e]; } else { s = d = e - EE; }
  int pos = atomicAdd(&cursor[d], 1);
  srcCSR[pos] = s;
}

// ---------------- compute ----------------
__device__ __forceinline__ float redsum32(float p){
  p += __shfl_xor(p, 1);
  p += __shfl_xor(p, 2);
  p += __shfl_xor(p, 4);
  p += __shfl_xor(p, 8);
  p += __shfl_xor(p, 16);
  return p;   // masks<=16 never cross the 32-lane half boundary
}

__device__ __forceinline__ float alpha_of(float dotp, float hls, float hrd){
  float a = (hls + hrd) * (1.f/(1.f + __expf(-dotp)));
  return (a >= 0.f) ? a : 0.2f*a;
}

// h0 = x@W0 + b0 ; hp0 = h0@Ws[0] ; hl0 = hp0.att_l[0] ; hr0 = hp0.att_r[0]
__global__ __launch_bounds__(256) void k_prologue(
    const float* __restrict__ x, const float* __restrict__ W0, const float* __restrict__ b0,
    const float* __restrict__ Ws0, const float* __restrict__ al0, const float* __restrict__ ar0,
    float* __restrict__ hp_out, float* __restrict__ hl_out, float* __restrict__ hr_out){
  __shared__ float w0[128*32];
  __shared__ float w1[32*32];
  int t = threadIdx.x;
  for (int i = t; i < 4096; i += 256) w0[i] = W0[i];
  for (int i = t; i < 1024; i += 256) w1[i] = Ws0[i];
  __syncthreads();
  int g = t >> 5, lane = t & 31;
  int n = blockIdx.x*8 + g;                 // 6250*8 == 50000, no bounds check
  const float4* x4 = (const float4*)(x + (size_t)n*128);
  float h = b0[lane];
  #pragma unroll
  for (int j4 = 0; j4 < 32; ++j4){
    float4 xv = x4[j4];
    h += xv.x * w0[(j4*4+0)*32 + lane];
    h += xv.y * w0[(j4*4+1)*32 + lane];
    h += xv.z * w0[(j4*4+2)*32 + lane];
    h += xv.w * w0[(j4*4+3)*32 + lane];
  }
  float hp = 0.f;
  #pragma unroll
  for (int j = 0; j < 32; ++j) hp += __shfl(h, j, 32) * w1[j*32 + lane];
  float tl = hp*al0[lane], tr = hp*ar0[lane];
  #pragma unroll
  for (int m = 1; m < 32; m <<= 1){ tl += __shfl_xor(tl, m); tr += __shfl_xor(tr, m); }
  hp_out[(size_t)n*32 + lane] = hp;
  if (lane == 0){ hl_out[n] = tl; hr_out[n] = tr; }
}

// One SuperGAT layer, fused. Pass 1: compute alpha once (cache to alphaBuf),
// track running max only (exp-free). Pass 2: e=exp(a-m); acc += v*e; den += e;
// normalize at end. Then relu(acc/den + b) + NEXT layer's transform fused.
__global__ __launch_bounds__(256) void k_layer(
    const float* __restrict__ hp, const float* __restrict__ hl, const float* __restrict__ hr,
    const int* __restrict__ offs, const int* __restrict__ srcCSR,
    const float* __restrict__ bcur,
    const float* __restrict__ Wn, const float* __restrict__ aln, const float* __restrict__ arn,
    const float* __restrict__ b16,
    float* __restrict__ alphaBuf,
    float* __restrict__ hp_out, float* __restrict__ hl_out, float* __restrict__ hr_out,
    float* __restrict__ final_out, int last){
  __shared__ float wl[1024];
  int t = threadIdx.x;
  int nW = last ? 512 : 1024;
  for (int i = t; i < nW; i += 256) wl[i] = Wn[i];
  __syncthreads();
  int g = t >> 5, lane = t & 31;
  int d = blockIdx.x*8 + g;
  float hpd = hp[(size_t)d*32 + lane];
  float hrd = hr[d];
  int beg = offs[d], end = offs[d+1];

  // ---- pass 1: alpha + running max (unrolled x2 for load/swizzle ILP) ----
  float m = -INFINITY;
  int i = beg;
  for (; i + 1 < end; i += 2){
    int s0 = srcCSR[i], s1 = srcCSR[i+1];
    float v0 = hp[(size_t)s0*32 + lane];
    float v1 = hp[(size_t)s1*32 + lane];
    float hl0 = hl[s0], hl1 = hl[s1];
    float p0 = redsum32(v0 * hpd);
    float p1 = redsum32(v1 * hpd);
    float a0 = alpha_of(p0, hl0, hrd);
    float a1 = alpha_of(p1, hl1, hrd);
    if (lane == 0){ alphaBuf[i] = a0; alphaBuf[i+1] = a1; }
    m = fmaxf(m, fmaxf(a0, a1));
  }
  if (i < end){
    int s0 = srcCSR[i];
    float v0 = hp[(size_t)s0*32 + lane];
    float p0 = redsum32(v0 * hpd);
    float a0 = alpha_of(p0, hl[s0], hrd);
    if (lane == 0) alphaBuf[i] = a0;
    m = fmaxf(m, a0);
  }

  // ---- pass 2: exp + weighted accumulate (unrolled x2, dual accumulators) ----
  float accA = 0.f, accB = 0.f, denA = 0.f, denB = 0.f;
  i = beg;
  for (; i + 1 < end; i += 2){
    int s0 = srcCSR[i], s1 = srcCSR[i+1];
    float a0 = alphaBuf[i], a1 = alphaBuf[i+1];
    float v0 = hp[(size_t)s0*32 + lane];
    float v1 = hp[(size_t)s1*32 + lane];
    float e0 = __expf(a0 - m), e1 = __expf(a1 - m);
    accA += v0 * e0; denA += e0;
    accB += v1 * e1; denB += e1;
  }
  if (i < end){
    int s0 = srcCSR[i];
    float a0 = alphaBuf[i];
    float v0 = hp[(size_t)s0*32 + lane];
    float e0 = __expf(a0 - m);
    accA += v0 * e0; denA += e0;
  }
  float acc = accA + accB;
  float den = denA + denB;
  float hnew = fmaxf(acc * (1.f/den) + bcur[lane], 0.f);

  if (!last){
    float hpn = 0.f;
    #pragma unroll
    for (int j = 0; j < 32; ++j) hpn += __shfl(hnew, j, 32) * wl[j*32 + lane];
    float tl = hpn*aln[lane], tr = hpn*arn[lane];
    #pragma unroll
    for (int mm = 1; mm < 32; mm <<= 1){ tl += __shfl_xor(tl, mm); tr += __shfl_xor(tr, mm); }
    hp_out[(size_t)d*32 + lane] = hpn;
    if (lane == 0){ hl_out[d] = tl; hr_out[d] = tr; }
  } else {
    int k = lane & 15;
    float o = b16[k];
    #pragma unroll
    for (int j = 0; j < 32; ++j) o += __shfl(hnew, j, 32) * wl[j*16 + k];
    if (lane < 16) final_out[(size_t)d*16 + lane] = o;
  }
}

extern "C" void kernel_launch(void* const* d_in, const int* in_sizes, int n_in,
                              void* d_out, int out_size, void* d_ws, size_t ws_size,
                              hipStream_t stream){
  const float* x   = (const float*)d_in[0];
  const int*   ei  = (const int*)  d_in[1];
  const float* W0  = (const float*)d_in[2];
  const float* b0  = (const float*)d_in[3];
  const float* Ws  = (const float*)d_in[4];
  const float* al  = (const float*)d_in[5];
  const float* ar  = (const float*)d_in[6];
  const float* bs  = (const float*)d_in[7];
  const float* W16 = (const float*)d_in[8];
  const float* b16 = (const float*)d_in[9];
  float* out = (float*)d_out;

  char* w = (char*)d_ws;
  int* count   = (int*)w;   w += 50176*sizeof(int);
  int* offs    = (int*)w;   w += 50176*sizeof(int);
  int* cursor  = (int*)w;   w += 50176*sizeof(int);
  int* srcCSR  = (int*)w;   w += 850048*sizeof(int);
  int* bsums   = (int*)w;   w += 256*sizeof(int);
  int* boffs   = (int*)w;   w += 256*sizeof(int);
  float* alphaBuf = (float*)w; w += 850048*sizeof(float);
  float* hpA   = (float*)w; w += (size_t)NN*32*sizeof(float);
  float* hpB   = (float*)w; w += (size_t)NN*32*sizeof(float);
  float* hlA   = (float*)w; w += 50176*sizeof(float);
  float* hrA   = (float*)w; w += 50176*sizeof(float);
  float* hlB   = (float*)w; w += 50176*sizeof(float);
  float* hrB   = (float*)w; w += 50176*sizeof(float);
  // total ~21 MB of d_ws

  // CSR build (rebuilt every call; ws is re-poisoned by the harness)
  k_zero   <<<196, 256, 0, stream>>>(count, NN);
  k_hist   <<<3321,256, 0, stream>>>(ei, count);
  k_bsum   <<<196, 256, 0, stream>>>(count, bsums);
  k_bscan  <<<1,   256, 0, stream>>>(bsums, boffs, 196);
  k_scan   <<<196, 256, 0, stream>>>(count, boffs, offs, cursor);
  k_scatter<<<3321,256, 0, stream>>>(ei, cursor, srcCSR);

  // h0 = x@W0+b0 fused with layer-0 transform
  k_prologue<<<6250, 256, 0, stream>>>(x, W0, b0, Ws, al, ar, hpA, hlA, hrA);

  for (int l = 0; l < 15; ++l){
    const float* hin  = (l & 1) ? hpB : hpA;
    const float* hlin = (l & 1) ? hlB : hlA;
    const float* hrin = (l & 1) ? hrB : hrA;
    float* hout  = (l & 1) ? hpA : hpB;
    float* hlout = (l & 1) ? hlA : hlB;
    float* hrout = (l & 1) ? hrA : hrB;
    int last = (l == 14);
    const float* Wn  = last ? W16 : (Ws + (size_t)(l+1)*1024);
    const float* aln = last ? al  : (al + (size_t)(l+1)*32);
    const float* arn = last ? ar  : (ar + (size_t)(l+1)*32);
    k_layer<<<6250, 256, 0, stream>>>(hin, hlin, hrin, offs, srcCSR,
                                      bs + (size_t)l*32,
                                      Wn, aln, arn, b16,
                                      alphaBuf,
                                      hout, hlout, hrout, out, last);
  }
}

// Round 3
// 838.227 us; speedup vs baseline: 2.3302x; 1.5229x over previous
//
#include <hip/hip_runtime.h>
#include <cmath>

#define NN 50000
#define EE 800000
#define ET 850000        // EE + NN self-loops
#define PADCAP 1000192   // >= ET + 3*NN, multiple of 256

// ---------------- CSR build ----------------
__global__ void k_zero(int* __restrict__ p, int n){
  int i = blockIdx.x*256 + threadIdx.x;
  if (i < n) p[i] = 0;
}

__global__ void k_fill(int* __restrict__ p){
  int i = blockIdx.x*256 + threadIdx.x;
  p[i] = NN;   // sentinel src for padding (grid sized exactly PADCAP/256)
}

__global__ void k_hist(const int* __restrict__ ei, int* __restrict__ count){
  int e = blockIdx.x*256 + threadIdx.x;
  if (e >= ET) return;
  int d = (e < EE) ? ei[EE + e] : (e - EE);
  atomicAdd(&count[d], 1);
}

__global__ void k_bsum(const int* __restrict__ count, int* __restrict__ bsums){
  int i = blockIdx.x*256 + threadIdx.x;
  int v = (i < NN) ? ((count[i] + 3) & ~3) : 0;   // padded counts
  #pragma unroll
  for (int m = 1; m < 64; m <<= 1) v += __shfl_xor(v, m);
  __shared__ int ws[4];
  if ((threadIdx.x & 63) == 0) ws[threadIdx.x >> 6] = v;
  __syncthreads();
  if (threadIdx.x == 0) bsums[blockIdx.x] = ws[0] + ws[1] + ws[2] + ws[3];
}

__global__ void k_bscan(const int* __restrict__ bsums, int* __restrict__ boffs, int nb){
  __shared__ int tmp[256];
  int t = threadIdx.x;
  int self = (t < nb) ? bsums[t] : 0;
  int v = self;
  for (int off = 1; off < 256; off <<= 1){
    tmp[t] = v; __syncthreads();
    int add = (t >= off) ? tmp[t - off] : 0;
    __syncthreads();
    v += add;
  }
  if (t < nb) boffs[t] = v - self;   // exclusive
}

__global__ void k_scan(const int* __restrict__ count, const int* __restrict__ boffs,
                       int* __restrict__ offs, int* __restrict__ cursor){
  __shared__ int tmp[256];
  int t = threadIdx.x;
  int gid = blockIdx.x*256 + t;
  int self = (gid < NN) ? ((count[gid] + 3) & ~3) : 0;   // padded counts
  int v = self;
  for (int off = 1; off < 256; off <<= 1){
    tmp[t] = v; __syncthreads();
    int add = (t >= off) ? tmp[t - off] : 0;
    __syncthreads();
    v += add;
  }
  int excl = v - self + boffs[blockIdx.x];
  if (gid < NN){ offs[gid] = excl; cursor[gid] = excl; }
  if (gid == NN-1) offs[NN] = excl + self;
}

__global__ void k_scatter(const int* __restrict__ ei, int* __restrict__ cursor,
                          int* __restrict__ srcCSR){
  int e = blockIdx.x*256 + threadIdx.x;
  if (e >= ET) return;
  int s, d;
  if (e < EE){ s = ei[e]; d = ei[EE + e]; } else { s = d = e - EE; }
  int pos = atomicAdd(&cursor[d], 1);
  srcCSR[pos] = s;
}

// ---------------- compute ----------------
__device__ __forceinline__ float redsum32(float p){
  p += __shfl_xor(p, 1);
  p += __shfl_xor(p, 2);
  p += __shfl_xor(p, 4);
  p += __shfl_xor(p, 8);
  p += __shfl_xor(p, 16);
  return p;   // masks<=16 never cross the 32-lane half boundary
}

// h0 = x@W0 + b0 ; hp0 = h0@Ws[0] ; hl0 = hp0.att_l[0] ; hr0 = hp0.att_r[0]
__global__ __launch_bounds__(256) void k_prologue(
    const float* __restrict__ x, const float* __restrict__ W0, const float* __restrict__ b0,
    const float* __restrict__ Ws0, const float* __restrict__ al0, const float* __restrict__ ar0,
    float* __restrict__ hp_out, float* __restrict__ hl_out, float* __restrict__ hr_out){
  __shared__ float w0[128*32];
  __shared__ float w1[32*32];
  int t = threadIdx.x;
  for (int i = t; i < 4096; i += 256) w0[i] = W0[i];
  for (int i = t; i < 1024; i += 256) w1[i] = Ws0[i];
  __syncthreads();
  int g = t >> 5, lane = t & 31;
  int n = blockIdx.x*8 + g;                 // 6250*8 == 50000, no bounds check
  const float4* x4 = (const float4*)(x + (size_t)n*128);
  float h = b0[lane];
  #pragma unroll
  for (int j4 = 0; j4 < 32; ++j4){
    float4 xv = x4[j4];
    h += xv.x * w0[(j4*4+0)*32 + lane];
    h += xv.y * w0[(j4*4+1)*32 + lane];
    h += xv.z * w0[(j4*4+2)*32 + lane];
    h += xv.w * w0[(j4*4+3)*32 + lane];
  }
  float hp = 0.f;
  #pragma unroll
  for (int j = 0; j < 32; ++j) hp += __shfl(h, j, 32) * w1[j*32 + lane];
  float tl = hp*al0[lane], tr = hp*ar0[lane];
  #pragma unroll
  for (int m = 1; m < 32; m <<= 1){ tl += __shfl_xor(tl, m); tr += __shfl_xor(tr, m); }
  hp_out[(size_t)n*32 + lane] = hp;
  if (lane == 0){ hl_out[n] = tl; hr_out[n] = tr; }
  if (blockIdx.x == 0 && t == 0) hl_out[NN] = -1e30f;   // pad sentinel
}

// One SuperGAT layer, single pass (no max-sub softmax), 4 edges batched per
// 32-lane group through one shared butterfly reduction. CSR segments padded
// to x4 with src=NN (hl[NN]=-1e30 -> e=0). Next layer's transform fused.
__global__ __launch_bounds__(256) void k_layer(
    const float* __restrict__ hp, const float* __restrict__ hl, const float* __restrict__ hr,
    const int* __restrict__ offs, const int* __restrict__ srcCSR,
    const float* __restrict__ bcur,
    const float* __restrict__ Wn, const float* __restrict__ aln, const float* __restrict__ arn,
    const float* __restrict__ b16,
    float* __restrict__ hp_out, float* __restrict__ hl_out, float* __restrict__ hr_out,
    float* __restrict__ final_out, int last){
  __shared__ float wl[1024];
  int t = threadIdx.x;
  int nW = last ? 512 : 1024;
  for (int i = t; i < nW; i += 256) wl[i] = Wn[i];
  __syncthreads();
  int g = t >> 5, lane = t & 31;
  int d = blockIdx.x*8 + g;
  float hpd = hp[(size_t)d*32 + lane];
  float hrd = hr[d];
  int beg = offs[d], end = offs[d+1];   // padded segment, multiple of 4

  float acc = 0.f, den = 0.f;
  for (int i = beg; i < end; i += 4){
    int4 s4 = *(const int4*)(srcCSR + i);
    // per-lane src for the hl gather: lane octets 0-7,8-15,16-23,24-31 own
    // edges 0,2,1,3 respectively (matches the reduce-tree output layout)
    int sA = (lane & 8)  ? s4.z : s4.x;
    int sB = (lane & 8)  ? s4.w : s4.y;
    int sx = (lane & 16) ? sB : sA;
    float hlx = hl[sx];
    float v0 = hp[((size_t)s4.x << 5) + lane];
    float v1 = hp[((size_t)s4.y << 5) + lane];
    float v2 = hp[((size_t)s4.z << 5) + lane];
    float v3 = hp[((size_t)s4.w << 5) + lane];
    float x0 = v0*hpd, x1 = v1*hpd, x2 = v2*hpd, x3 = v3*hpd;
    // batched 4-edge butterfly reduce (21 ops for 4 dots)
    float y0 = x0 + __shfl_xor(x0, 16);
    float y1 = x1 + __shfl_xor(x1, 16);
    float y2 = x2 + __shfl_xor(x2, 16);
    float y3 = x3 + __shfl_xor(x3, 16);
    float pA = (lane & 16) ? y1 : y0;
    float pB = (lane & 16) ? y3 : y2;
    float qA = pA + __shfl_xor(pA, 8);
    float qB = pB + __shfl_xor(pB, 8);
    float q  = (lane & 8) ? qB : qA;
    q += __shfl_xor(q, 4);
    q += __shfl_xor(q, 2);
    q += __shfl_xor(q, 1);
    // q = dot(hi,hj) for this lane's edge; one transcendental chain per lane
    float a = (hlx + hrd) * (1.f/(1.f + __expf(-q)));
    a = (a >= 0.f) ? a : 0.2f*a;
    float e = __expf(a);          // no max-sub: mathematically identical
    den += e;                     // each e counted 8x; fixed below
    float e0 = __shfl(e, 0, 32);
    float e1 = __shfl(e, 16, 32);
    float e2 = __shfl(e, 8, 32);
    float e3 = __shfl(e, 24, 32);
    acc += v0*e0; acc += v1*e1; acc += v2*e2; acc += v3*e3;
  }
  float dent = redsum32(den) * 0.125f;
  float hnew = fmaxf(acc * (1.f/dent) + bcur[lane], 0.f);

  if (!last){
    float hpn = 0.f;
    #pragma unroll
    for (int j = 0; j < 32; ++j) hpn += __shfl(hnew, j, 32) * wl[j*32 + lane];
    float tl = hpn*aln[lane], tr = hpn*arn[lane];
    #pragma unroll
    for (int mm = 1; mm < 32; mm <<= 1){ tl += __shfl_xor(tl, mm); tr += __shfl_xor(tr, mm); }
    hp_out[(size_t)d*32 + lane] = hpn;
    if (lane == 0){ hl_out[d] = tl; hr_out[d] = tr; }
    if (blockIdx.x == 0 && t == 0) hl_out[NN] = -1e30f;   // pad sentinel
  } else {
    int k = lane & 15;
    float o = b16[k];
    #pragma unroll
    for (int j = 0; j < 32; ++j) o += __shfl(hnew, j, 32) * wl[j*16 + k];
    if (lane < 16) final_out[(size_t)d*16 + lane] = o;
  }
}

extern "C" void kernel_launch(void* const* d_in, const int* in_sizes, int n_in,
                              void* d_out, int out_size, void* d_ws, size_t ws_size,
                              hipStream_t stream){
  const float* x   = (const float*)d_in[0];
  const int*   ei  = (const int*)  d_in[1];
  const float* W0  = (const float*)d_in[2];
  const float* b0  = (const float*)d_in[3];
  const float* Ws  = (const float*)d_in[4];
  const float* al  = (const float*)d_in[5];
  const float* ar  = (const float*)d_in[6];
  const float* bs  = (const float*)d_in[7];
  const float* W16 = (const float*)d_in[8];
  const float* b16 = (const float*)d_in[9];
  float* out = (float*)d_out;

  char* w = (char*)d_ws;
  int* count   = (int*)w;   w += 50176*sizeof(int);
  int* offs    = (int*)w;   w += 50176*sizeof(int);
  int* cursor  = (int*)w;   w += 50176*sizeof(int);
  int* srcCSR  = (int*)w;   w += (size_t)PADCAP*sizeof(int);
  int* bsums   = (int*)w;   w += 256*sizeof(int);
  int* boffs   = (int*)w;   w += 256*sizeof(int);
  float* hpA   = (float*)w; w += (size_t)(NN+1)*32*sizeof(float);
  float* hpB   = (float*)w; w += (size_t)(NN+1)*32*sizeof(float);
  float* hlA   = (float*)w; w += 50176*sizeof(float);
  float* hrA   = (float*)w; w += 50176*sizeof(float);
  float* hlB   = (float*)w; w += 50176*sizeof(float);
  float* hrB   = (float*)w; w += 50176*sizeof(float);
  // total ~21.5 MB of d_ws

  // CSR build (rebuilt every call; ws is re-poisoned by the harness)
  k_zero   <<<196, 256, 0, stream>>>(count, NN);
  k_fill   <<<PADCAP/256, 256, 0, stream>>>(srcCSR);
  k_hist   <<<3321,256, 0, stream>>>(ei, count);
  k_bsum   <<<196, 256, 0, stream>>>(count, bsums);
  k_bscan  <<<1,   256, 0, stream>>>(bsums, boffs, 196);
  k_scan   <<<196, 256, 0, stream>>>(count, boffs, offs, cursor);
  k_scatter<<<3321,256, 0, stream>>>(ei, cursor, srcCSR);

  // h0 = x@W0+b0 fused with layer-0 transform
  k_prologue<<<6250, 256, 0, stream>>>(x, W0, b0, Ws, al, ar, hpA, hlA, hrA);

  for (int l = 0; l < 15; ++l){
    const float* hin  = (l & 1) ? hpB : hpA;
    const float* hlin = (l & 1) ? hlB : hlA;
    const float* hrin = (l & 1) ? hrB : hrA;
    float* hout  = (l & 1) ? hpA : hpB;
    float* hlout = (l & 1) ? hlA : hlB;
    float* hrout = (l & 1) ? hrA : hrB;
    int last = (l == 14);
    const float* Wn  = last ? W16 : (Ws + (size_t)(l+1)*1024);
    const float* aln = last ? al  : (al + (size_t)(l+1)*32);
    const float* arn = last ? ar  : (ar + (size_t)(l+1)*32);
    k_layer<<<6250, 256, 0, stream>>>(hin, hlin, hrin, offs, srcCSR,
                                      bs + (size_t)l*32,
                                      Wn, aln, arn, b16,
                                      hout, hlout, hrout, out, last);
  }
}

// Round 4
// 746.009 us; speedup vs baseline: 2.6183x; 1.1236x over previous
//
#include <hip/hip_runtime.h>
#include <cmath>

#define NN 50000
#define EE 800000
#define ET 850000        // EE + NN self-loops
#define PADCAP 1200128   // >= ET + 7*NN, multiple of 256

// ---------------- CSR build ----------------
__global__ void k_zero(int* __restrict__ p, int n){
  int i = blockIdx.x*256 + threadIdx.x;
  if (i < n) p[i] = 0;
}

__global__ void k_fill(int* __restrict__ p){
  int i = blockIdx.x*256 + threadIdx.x;
  p[i] = NN;   // sentinel src for padding (grid sized exactly PADCAP/256)
}

__global__ void k_hist(const int* __restrict__ ei, int* __restrict__ count){
  int e = blockIdx.x*256 + threadIdx.x;
  if (e >= ET) return;
  int d = (e < EE) ? ei[EE + e] : (e - EE);
  atomicAdd(&count[d], 1);
}

__global__ void k_bsum(const int* __restrict__ count, int* __restrict__ bsums){
  int i = blockIdx.x*256 + threadIdx.x;
  int v = (i < NN) ? ((count[i] + 7) & ~7) : 0;   // padded to x8
  #pragma unroll
  for (int m = 1; m < 64; m <<= 1) v += __shfl_xor(v, m);
  __shared__ int ws[4];
  if ((threadIdx.x & 63) == 0) ws[threadIdx.x >> 6] = v;
  __syncthreads();
  if (threadIdx.x == 0) bsums[blockIdx.x] = ws[0] + ws[1] + ws[2] + ws[3];
}

__global__ void k_bscan(const int* __restrict__ bsums, int* __restrict__ boffs, int nb){
  __shared__ int tmp[256];
  int t = threadIdx.x;
  int self = (t < nb) ? bsums[t] : 0;
  int v = self;
  for (int off = 1; off < 256; off <<= 1){
    tmp[t] = v; __syncthreads();
    int add = (t >= off) ? tmp[t - off] : 0;
    __syncthreads();
    v += add;
  }
  if (t < nb) boffs[t] = v - self;   // exclusive
}

__global__ void k_scan(const int* __restrict__ count, const int* __restrict__ boffs,
                       int* __restrict__ offs, int* __restrict__ cursor){
  __shared__ int tmp[256];
  int t = threadIdx.x;
  int gid = blockIdx.x*256 + t;
  int self = (gid < NN) ? ((count[gid] + 7) & ~7) : 0;   // padded to x8
  int v = self;
  for (int off = 1; off < 256; off <<= 1){
    tmp[t] = v; __syncthreads();
    int add = (t >= off) ? tmp[t - off] : 0;
    __syncthreads();
    v += add;
  }
  int excl = v - self + boffs[blockIdx.x];
  if (gid < NN){ offs[gid] = excl; cursor[gid] = excl; }
  if (gid == NN-1) offs[NN] = excl + self;
}

__global__ void k_scatter(const int* __restrict__ ei, int* __restrict__ cursor,
                          int* __restrict__ srcCSR){
  int e = blockIdx.x*256 + threadIdx.x;
  if (e >= ET) return;
  int s, d;
  if (e < EE){ s = ei[e]; d = ei[EE + e]; } else { s = d = e - EE; }
  int pos = atomicAdd(&cursor[d], 1);
  srcCSR[pos] = s;
}

// ---------------- compute ----------------
__device__ __forceinline__ float redsum32(float p){
  p += __shfl_xor(p, 1);
  p += __shfl_xor(p, 2);
  p += __shfl_xor(p, 4);
  p += __shfl_xor(p, 8);
  p += __shfl_xor(p, 16);
  return p;
}

// h0 = x@W0 + b0 ; hp0 = h0@Ws[0] ; hl0 = hp0.att_l[0] ; hr0 = hp0.att_r[0]
__global__ __launch_bounds__(256) void k_prologue(
    const float* __restrict__ x, const float* __restrict__ W0, const float* __restrict__ b0,
    const float* __restrict__ Ws0, const float* __restrict__ al0, const float* __restrict__ ar0,
    float* __restrict__ hp_out, float* __restrict__ hl_out, float* __restrict__ hr_out){
  __shared__ float w0[128*32];
  __shared__ float w1[32*32];
  int t = threadIdx.x;
  for (int i = t; i < 4096; i += 256) w0[i] = W0[i];
  for (int i = t; i < 1024; i += 256) w1[i] = Ws0[i];
  __syncthreads();
  int g = t >> 5, lane = t & 31;
  int n = blockIdx.x*8 + g;                 // 6250*8 == 50000, no bounds check
  const float4* x4 = (const float4*)(x + (size_t)n*128);
  float h = b0[lane];
  #pragma unroll
  for (int j4 = 0; j4 < 32; ++j4){
    float4 xv = x4[j4];
    h += xv.x * w0[(j4*4+0)*32 + lane];
    h += xv.y * w0[(j4*4+1)*32 + lane];
    h += xv.z * w0[(j4*4+2)*32 + lane];
    h += xv.w * w0[(j4*4+3)*32 + lane];
  }
  float hp = 0.f;
  #pragma unroll
  for (int j = 0; j < 32; ++j) hp += __shfl(h, j, 32) * w1[j*32 + lane];
  float tl = hp*al0[lane], tr = hp*ar0[lane];
  #pragma unroll
  for (int m = 1; m < 32; m <<= 1){ tl += __shfl_xor(tl, m); tr += __shfl_xor(tr, m); }
  hp_out[(size_t)n*32 + lane] = hp;
  if (lane == 0){ hl_out[n] = tl; hr_out[n] = tr; }
  if (blockIdx.x == 0){
    if (g == 0) hp_out[(size_t)NN*32 + lane] = 0.f;   // pad row
    if (t == 0) hl_out[NN] = -1e30f;                  // pad sentinel -> e=0
  }
}

// One SuperGAT layer. Feature-split: octet (8 lanes) owns one edge, each lane
// holds 4 features (float4). Per 8 edges: 2 gather instrs + 2x(dot4 + 3-step
// octet reduce + transcendental chain + 4 FMA accumulate). CSR padded to x8.
__global__ __launch_bounds__(256) void k_layer(
    const float* __restrict__ hp, const float* __restrict__ hl, const float* __restrict__ hr,
    const int* __restrict__ offs, const int* __restrict__ srcCSR,
    const float* __restrict__ bcur,
    const float* __restrict__ Wn, const float* __restrict__ aln, const float* __restrict__ arn,
    const float* __restrict__ b16,
    float* __restrict__ hp_out, float* __restrict__ hl_out, float* __restrict__ hr_out,
    float* __restrict__ final_out, int last){
  __shared__ float wl[1024];
  __shared__ float xbuf[8*32];
  int t = threadIdx.x;
  int nW = last ? 512 : 1024;
  for (int i = t; i < nW; i += 256) wl[i] = Wn[i];
  __syncthreads();
  int g = t >> 5, lane = t & 31;
  int oct = lane >> 3, li = lane & 7;
  int d = blockIdx.x*8 + g;
  float4 hpd4 = *(const float4*)(hp + (size_t)d*32 + li*4);
  float hrd = hr[d];
  int beg = offs[d], end = offs[d+1];   // padded segment, multiple of 8

  float4 acc = {0.f,0.f,0.f,0.f};
  float den = 0.f;
  for (int i = beg; i < end; i += 8){
    int4 sa = *(const int4*)(srcCSR + i);
    int4 sb = *(const int4*)(srcCSR + i + 4);
    int sxa = (oct & 1) ? sa.y : sa.x;
    int sya = (oct & 1) ? sa.w : sa.z;
    int s_a = (oct & 2) ? sya : sxa;
    int sxb = (oct & 1) ? sb.y : sb.x;
    int syb = (oct & 1) ? sb.w : sb.z;
    int s_b = (oct & 2) ? syb : sxb;
    float4 va = *((const float4*)(hp + ((size_t)s_a << 5)) + li);
    float4 vb = *((const float4*)(hp + ((size_t)s_b << 5)) + li);
    float hla = hl[s_a];
    float hlb = hl[s_b];
    // chain A
    float pa = va.x*hpd4.x + va.y*hpd4.y + va.z*hpd4.z + va.w*hpd4.w;
    pa += __shfl_xor(pa, 1); pa += __shfl_xor(pa, 2); pa += __shfl_xor(pa, 4);
    float aa = (hla + hrd) * (1.f/(1.f + __expf(-pa)));
    aa = fmaxf(aa, 0.2f*aa);
    float ea = __expf(aa);
    den += ea;
    acc.x += va.x*ea; acc.y += va.y*ea; acc.z += va.z*ea; acc.w += va.w*ea;
    // chain B
    float pb = vb.x*hpd4.x + vb.y*hpd4.y + vb.z*hpd4.z + vb.w*hpd4.w;
    pb += __shfl_xor(pb, 1); pb += __shfl_xor(pb, 2); pb += __shfl_xor(pb, 4);
    float ab = (hlb + hrd) * (1.f/(1.f + __expf(-pb)));
    ab = fmaxf(ab, 0.2f*ab);
    float eb = __expf(ab);
    den += eb;
    acc.x += vb.x*eb; acc.y += vb.y*eb; acc.z += vb.z*eb; acc.w += vb.w*eb;
  }
  // cross-octet reduce: lanes sharing li sum their 4 features over all octets
  #pragma unroll
  for (int m = 8; m < 32; m <<= 1){
    acc.x += __shfl_xor(acc.x, m);
    acc.y += __shfl_xor(acc.y, m);
    acc.z += __shfl_xor(acc.z, m);
    acc.w += __shfl_xor(acc.w, m);
  }
  float rdent = 8.f / redsum32(den);   // each e counted 8x (one per octet lane)
  if (oct == 0) *(float4*)(&xbuf[g*32 + li*4]) = acc;
  __syncthreads();
  float hnew = fmaxf(xbuf[g*32 + lane]*rdent + bcur[lane], 0.f);

  if (!last){
    float hpn = 0.f;
    #pragma unroll
    for (int j = 0; j < 32; ++j) hpn += __shfl(hnew, j, 32) * wl[j*32 + lane];
    float tl = hpn*aln[lane], tr = hpn*arn[lane];
    #pragma unroll
    for (int mm = 1; mm < 32; mm <<= 1){ tl += __shfl_xor(tl, mm); tr += __shfl_xor(tr, mm); }
    hp_out[(size_t)d*32 + lane] = hpn;
    if (lane == 0){ hl_out[d] = tl; hr_out[d] = tr; }
    if (blockIdx.x == 0){
      if (g == 0) hp_out[(size_t)NN*32 + lane] = 0.f;
      if (t == 0) hl_out[NN] = -1e30f;
    }
  } else {
    int k = lane & 15;
    float o = b16[k];
    #pragma unroll
    for (int j = 0; j < 32; ++j) o += __shfl(hnew, j, 32) * wl[j*16 + k];
    if (lane < 16) final_out[(size_t)d*16 + lane] = o;
  }
}

extern "C" void kernel_launch(void* const* d_in, const int* in_sizes, int n_in,
                              void* d_out, int out_size, void* d_ws, size_t ws_size,
                              hipStream_t stream){
  const float* x   = (const float*)d_in[0];
  const int*   ei  = (const int*)  d_in[1];
  const float* W0  = (const float*)d_in[2];
  const float* b0  = (const float*)d_in[3];
  const float* Ws  = (const float*)d_in[4];
  const float* al  = (const float*)d_in[5];
  const float* ar  = (const float*)d_in[6];
  const float* bs  = (const float*)d_in[7];
  const float* W16 = (const float*)d_in[8];
  const float* b16 = (const float*)d_in[9];
  float* out = (float*)d_out;

  char* w = (char*)d_ws;
  int* count   = (int*)w;   w += 50176*sizeof(int);
  int* offs    = (int*)w;   w += 50176*sizeof(int);
  int* cursor  = (int*)w;   w += 50176*sizeof(int);
  int* srcCSR  = (int*)w;   w += (size_t)PADCAP*sizeof(int);
  int* bsums   = (int*)w;   w += 256*sizeof(int);
  int* boffs   = (int*)w;   w += 256*sizeof(int);
  float* hpA   = (float*)w; w += (size_t)(NN+1)*32*sizeof(float);
  float* hpB   = (float*)w; w += (size_t)(NN+1)*32*sizeof(float);
  float* hlA   = (float*)w; w += 50176*sizeof(float);
  float* hrA   = (float*)w; w += 50176*sizeof(float);
  float* hlB   = (float*)w; w += 50176*sizeof(float);
  float* hrB   = (float*)w; w += 50176*sizeof(float);
  // total ~22.3 MB of d_ws

  // CSR build (rebuilt every call; ws is re-poisoned by the harness)
  k_zero   <<<196, 256, 0, stream>>>(count, NN);
  k_fill   <<<PADCAP/256, 256, 0, stream>>>(srcCSR);
  k_hist   <<<3321,256, 0, stream>>>(ei, count);
  k_bsum   <<<196, 256, 0, stream>>>(count, bsums);
  k_bscan  <<<1,   256, 0, stream>>>(bsums, boffs, 196);
  k_scan   <<<196, 256, 0, stream>>>(count, boffs, offs, cursor);
  k_scatter<<<3321,256, 0, stream>>>(ei, cursor, srcCSR);

  // h0 = x@W0+b0 fused with layer-0 transform
  k_prologue<<<6250, 256, 0, stream>>>(x, W0, b0, Ws, al, ar, hpA, hlA, hrA);

  for (int l = 0; l < 15; ++l){
    const float* hin  = (l & 1) ? hpB : hpA;
    const float* hlin = (l & 1) ? hlB : hlA;
    const float* hrin = (l & 1) ? hrB : hrA;
    float* hout  = (l & 1) ? hpA : hpB;
    float* hlout = (l & 1) ? hlA : hlB;
    float* hrout = (l & 1) ? hrA : hrB;
    int last = (l == 14);
    const float* Wn  = last ? W16 : (Ws + (size_t)(l+1)*1024);
    const float* aln = last ? al  : (al + (size_t)(l+1)*32);
    const float* arn = last ? ar  : (ar + (size_t)(l+1)*32);
    k_layer<<<6250, 256, 0, stream>>>(hin, hlin, hrin, offs, srcCSR,
                                      bs + (size_t)l*32,
                                      Wn, aln, arn, b16,
                                      hout, hlout, hrout, out, last);
  }
}